// Round 8
// baseline (754.287 us; speedup 1.0000x reference)
//
#include <hip/hip_runtime.h>
#include <hip/hip_bf16.h>

#define NROWS 8192
#define DIM   512
#define KNN   32
#define NPAIR 2048

#define STRIPS 8
#define SCOLS  1024              // cols per strip (2MB hi+lo -> L2-resident/XCD)
#define CHUNK  256               // cols per selection chunk
#define CHUNKS (SCOLS / CHUNK)   // 4
#define KSTEPS (DIM / 16)        // 32 (BK=16)
#define NSTEP  (CHUNKS * KSTEPS) // 128
#define MROWS  128               // rows per WG
#define SSTR   48                // padded candidates per strip (192B aligned)
#define NCANDP (STRIPS * SSTR)   // 384

typedef __attribute__((ext_vector_type(8)))  short bf16x8;
typedef __attribute__((ext_vector_type(16))) float f32x16;

#define WAITV(N) asm volatile("s_waitcnt vmcnt(" #N ")" ::: "memory")
#define LGKM0()  asm volatile("s_waitcnt lgkmcnt(0)" ::: "memory")
#define RD(off)  (*(const bf16x8*)(smem + (off)))
#define MFMA(a, b, c) __builtin_amdgcn_mfma_f32_32x32x16_bf16((a), (b), (c), 0, 0, 0)

__device__ __forceinline__ void gload16(const void* g, void* l) {
    __builtin_amdgcn_global_load_lds(
        (const __attribute__((address_space(1))) void*)g,
        (__attribute__((address_space(3))) void*)l, 16, 0, 0);
}

__device__ __forceinline__ unsigned short bfrne(float x) {
    unsigned u = __float_as_uint(x);
    return (unsigned short)((u + 0x7FFFu + ((u >> 16) & 1u)) >> 16);
}

// ---------------- row squared norms ----------------
__global__ __launch_bounds__(256) void sqnorm_k(const float* __restrict__ E,
                                                float* __restrict__ sq) {
    int row  = blockIdx.x * 4 + (threadIdx.x >> 6);
    int lane = threadIdx.x & 63;
    const float4* e4 = reinterpret_cast<const float4*>(E + (size_t)row * DIM);
    float acc = 0.f;
#pragma unroll
    for (int t = 0; t < 2; ++t) {
        float4 v = e4[lane + 64 * t];
        acc += v.x * v.x + v.y * v.y + v.z * v.z + v.w * v.w;
    }
#pragma unroll
    for (int off = 32; off; off >>= 1) acc += __shfl_xor(acc, off);
    if (lane == 0) sq[row] = acc;
}

// ---------------- split fp32 -> bf16 hi/lo, packed in MFMA-fragment order ----
__global__ __launch_bounds__(256) void prep_k(const float* __restrict__ E,
                                              short* __restrict__ Phi,
                                              short* __restrict__ Plo) {
    const int p    = blockIdx.x * 256 + threadIdx.x;
    const int lane = p & 63;
    const int s    = (p >> 6) & 31;
    const int rb   = p >> 11;
    const int row  = rb * 32 + (lane & 31);
    const int k0   = s * 16 + (lane >> 5) * 8;
    const float4* src = reinterpret_cast<const float4*>(E + (size_t)row * DIM + k0);
    float4 x0 = src[0], x1 = src[1];
    float xs[8] = {x0.x, x0.y, x0.z, x0.w, x1.x, x1.y, x1.z, x1.w};
    short hs[8], ls[8];
#pragma unroll
    for (int e = 0; e < 8; ++e) {
        unsigned short hb = bfrne(xs[e]);
        float hf = __uint_as_float(((unsigned)hb) << 16);
        hs[e] = (short)hb;
        ls[e] = (short)bfrne(xs[e] - hf);
    }
    bf16x8 h, l;
#pragma unroll
    for (int e = 0; e < 8; ++e) { h[e] = hs[e]; l[e] = ls[e]; }
    *reinterpret_cast<bf16x8*>(Phi + (size_t)p * 8) = h;
    *reinterpret_cast<bf16x8*>(Plo + (size_t)p * 8) = l;
}

// ---------------- fused distance-GEMM + strip top-33 ----------------
// 512 thr, 8 waves (2rg x 4cg), WG tile 128x256, per-wave 64x64
// (8 ds_read : 12 MFMA). LDS 64KB (dbuf A16+B32+SC16) -> 2 WGs/CU.
// Counted vmcnt(3) + raw s_barrier: staging loads stay in flight across
// barriers; incremental staging pointers (strength-reduced); selection
// barriers are lgkmcnt-only. Grid 512 = 2/CU, st = bid&7 = XCD strip.
__global__ __launch_bounds__(512, 4) void distsel_k(const short* __restrict__ Phi,
                                                    const short* __restrict__ Plo,
                                                    const float* __restrict__ sq,
                                                    float* __restrict__ cval,
                                                    int* __restrict__ cidx) {
    extern __shared__ char smem[];
    // At: [buf2][slot8: m*4+rb][512 shorts]   = 16 KB  (base 0)
    // Bt: [buf2][slot16: m*8+cb][512 shorts]  = 32 KB  (base 16384)
    // SC: [16][256] f32                       = 16 KB  (base 49152)
    float* SC = (float*)(smem + 49152);

    const int tid  = threadIdx.x;
    const int w    = tid >> 6;
    const int lane = tid & 63;
    const int kh   = lane >> 5;
    const int c32  = lane & 31;
    const int rg   = w >> 2;
    const int cg   = w & 3;
    const int rbk  = blockIdx.x >> 3;
    const int st   = blockIdx.x & 7;
    const int r0   = rbk * MROWS;
    const int cstrip = st * SCOLS;
    const float INF_F = __builtin_inff();
    const int laneoff = lane * 16;

    const int mat = w >> 2;                    // waves 0-3 stage hi, 4-7 lo
    const short* __restrict__ Pm = mat ? Plo : Phi;

    // staging pointers (always point at the NEXT stage's source)
    const short* pA  = Pm + (size_t)((r0 >> 5) + (w & 3)) * 16384 + lane * 8;
    const short* pB0 = Pm + (size_t)((cstrip >> 5) + ((2 * w) & 7)) * 16384 + lane * 8;
    const short* pB1 = pB0 + 16384;
    const int dstA = w * 1024;                                      // + buf*8192
    const int dstB = 16384 + ((w >> 2) * 8 + ((2 * w) & 7)) * 1024; // + buf*16384

    float Tv[16]; int Ti[16];
#pragma unroll
    for (int r = 0; r < 16; ++r) { Tv[r] = INF_F; Ti[r] = -1; }

    f32x16 acc[2][2];
#pragma unroll
    for (int rbs = 0; rbs < 2; ++rbs)
#pragma unroll
        for (int ci = 0; ci < 2; ++ci)
#pragma unroll
            for (int m = 0; m < 16; ++m) acc[rbs][ci][m] = 0.f;

    // chunk-end: write scores (8 phases of 16 rows) + top-33 insertion
    auto selchunk = [&](int ch) {
        const int c0 = cstrip + ch * CHUNK;
        const float sqv0 = sq[c0 + cg * 64 + c32];
        const float sqv1 = sq[c0 + cg * 64 + 32 + c32];
#pragma unroll
        for (int q = 0; q < 8; ++q) {
            if (rg == (q >> 2)) {
                const int rbs = (q >> 1) & 1;
                const int mh  = (q & 1) * 8;
#pragma unroll
                for (int ci = 0; ci < 2; ++ci) {
                    const float sv = ci ? sqv1 : sqv0;
#pragma unroll
                    for (int mm = 0; mm < 8; ++mm) {
                        const int m = mh + mm;
                        const int sub15 = (m & 3) + 8 * ((m >> 2) & 1) + 4 * kh;
                        SC[sub15 * CHUNK + cg * 64 + ci * 32 + c32] = sv - 2.f * acc[rbs][ci][m];
                    }
                }
            }
            LGKM0();
            __builtin_amdgcn_s_barrier();
            __builtin_amdgcn_sched_barrier(0);
#pragma unroll
            for (int rr = 0; rr < 2; ++rr) {
                float& tv = Tv[q * 2 + rr];
                int&   ti = Ti[q * 2 + rr];
                const float4 f = *(const float4*)(SC + (2 * w + rr) * CHUNK + 4 * lane);
                float mn = fminf(fminf(f.x, f.y), fminf(f.z, f.w));
                float t0e = INF_F;
                if (ch == 0) {
                    // bitonic-sort the 64 per-lane mins; 33rd smallest is a
                    // valid upper bound on the chunk's true 33rd smallest.
                    float v = mn;
#pragma unroll
                    for (int k = 2; k <= 64; k <<= 1)
#pragma unroll
                        for (int j = k >> 1; j; j >>= 1) {
                            float o = __shfl_xor(v, j);
                            const bool lower = ((lane & j) == 0);
                            const bool dir   = ((lane & k) == 0);
                            v = (lower == dir) ? fminf(v, o) : fmaxf(v, o);
                        }
                    float t0 = __shfl(v, 32);
                    t0e = t0 + fabsf(t0) * 1e-6f + 1e-30f;   // nudge up
                }
                float lthr = __shfl(tv, 32);
                float gate = fminf(lthr, t0e);
                while (true) {
                    unsigned long long bal = __ballot(mn < gate);
                    if (!bal) break;
                    const int src = (int)__builtin_ctzll(bal);
                    const float gx = __shfl(f.x, src);
                    const float gy = __shfl(f.y, src);
                    const float gz = __shfl(f.z, src);
                    const float gw = __shfl(f.w, src);
                    const int jc0 = c0 + 4 * src;
                    if (lane == src) mn = INF_F;
#define INS(VV, JJ)                                                         \
                    if ((VV) < gate) {                                      \
                        float pv = __shfl_up(tv, 1);                        \
                        int   pi = __shfl_up(ti, 1);                        \
                        if (lane == 0) pv = -INF_F;                         \
                        if (tv > (VV)) {                                    \
                            const bool tk = pv > (VV);                      \
                            tv = tk ? pv : (VV);                            \
                            ti = tk ? pi : (JJ);                            \
                        }                                                   \
                        lthr = __shfl(tv, 32);                              \
                        gate = fminf(lthr, t0e);                            \
                    }
                    INS(gx, jc0); INS(gy, jc0 + 1); INS(gz, jc0 + 2); INS(gw, jc0 + 3);
#undef INS
                }
            }
            LGKM0();
            __builtin_amdgcn_s_barrier();
            __builtin_amdgcn_sched_barrier(0);
        }
#pragma unroll
        for (int rbs = 0; rbs < 2; ++rbs)
#pragma unroll
            for (int ci = 0; ci < 2; ++ci)
#pragma unroll
                for (int m = 0; m < 16; ++m) acc[rbs][ci][m] = 0.f;
    };

    // prologue: stage step 0 into buf 0
    gload16(pA,  smem + dstA);
    gload16(pB0, smem + dstB);
    gload16(pB1, smem + dstB + 1024);
    pA += 512; pB0 += 512; pB1 += 512;

#define STEP(T, BUF)                                                           \
    {                                                                          \
        if ((T) + 1 < NSTEP) {                                                 \
            gload16(pA,  smem + (((BUF) ^ 1) * 8192)  + dstA);                 \
            gload16(pB0, smem + (((BUF) ^ 1) * 16384) + dstB);                 \
            gload16(pB1, smem + (((BUF) ^ 1) * 16384) + dstB + 1024);          \
            if ((((T) + 1) & 31) == 31) { pA -= 15872; pB0 += 115200; pB1 += 115200; } \
            else { pA += 512; pB0 += 512; pB1 += 512; }                        \
            WAITV(3);                                                          \
        } else {                                                               \
            WAITV(0);                                                          \
        }                                                                      \
        __builtin_amdgcn_s_barrier();                                          \
        __builtin_amdgcn_sched_barrier(0);                                     \
        const int aoff = (BUF) * 8192 + rg * 2048 + laneoff;                   \
        const int boff = 16384 + (BUF) * 16384 + cg * 2048 + laneoff;          \
        bf16x8 ah0 = RD(aoff),        ah1 = RD(aoff + 1024);                   \
        bf16x8 al0 = RD(aoff + 4096), al1 = RD(aoff + 5120);                   \
        bf16x8 bh0 = RD(boff),        bh1 = RD(boff + 1024);                   \
        bf16x8 bl0 = RD(boff + 8192), bl1 = RD(boff + 9216);                   \
        acc[0][0] = MFMA(ah0, bh0, acc[0][0]);                                 \
        acc[0][0] = MFMA(ah0, bl0, acc[0][0]);                                 \
        acc[0][0] = MFMA(al0, bh0, acc[0][0]);                                 \
        acc[0][1] = MFMA(ah0, bh1, acc[0][1]);                                 \
        acc[0][1] = MFMA(ah0, bl1, acc[0][1]);                                 \
        acc[0][1] = MFMA(al0, bh1, acc[0][1]);                                 \
        acc[1][0] = MFMA(ah1, bh0, acc[1][0]);                                 \
        acc[1][0] = MFMA(ah1, bl0, acc[1][0]);                                 \
        acc[1][0] = MFMA(al1, bh0, acc[1][0]);                                 \
        acc[1][1] = MFMA(ah1, bh1, acc[1][1]);                                 \
        acc[1][1] = MFMA(ah1, bl1, acc[1][1]);                                 \
        acc[1][1] = MFMA(al1, bh1, acc[1][1]);                                 \
        if (((T) & 31) == 31) selchunk((T) >> 5);                              \
        LGKM0();                                                               \
        __builtin_amdgcn_s_barrier();                                          \
        __builtin_amdgcn_sched_barrier(0);                                     \
    }

    for (int tt = 0; tt < NSTEP; tt += 2) {
        STEP(tt, 0)
        STEP(tt + 1, 1)
    }
#undef STEP

    // emit: padded 48-entry strip segments (192B aligned, no partial lines)
#pragma unroll
    for (int p = 0; p < 16; ++p) {
        const int grow = r0 + (p >> 1) * 16 + 2 * w + (p & 1);
        if (lane < SSTR) {
            const bool real = lane <= 32;
            cval[(size_t)grow * NCANDP + st * SSTR + lane] = real ? Tv[p] : INF_F;
            cidx[(size_t)grow * NCANDP + st * SSTR + lane] = real ? Ti[p] : 0x7FFFFFFF;
        }
    }
}

// ---------------- merge strips: global top-33 of 384 (padded), drop self ----
__global__ __launch_bounds__(256) void merge_k(const float* __restrict__ cval,
                                               const int* __restrict__ cidx,
                                               int* __restrict__ knn) {
    const int row  = blockIdx.x * 4 + (threadIdx.x >> 6);
    const int lane = threadIdx.x & 63;
    const float INF_F = __builtin_inff();
    const float* cv = cval + (size_t)row * NCANDP;
    const int*   ci = cidx + (size_t)row * NCANDP;
    float vv[6]; int ii[6];
#pragma unroll
    for (int k = 0; k < 6; ++k) {
        vv[k] = cv[lane + 64 * k];
        ii[k] = ci[lane + 64 * k];
    }
    for (int it = 0; it < 33; ++it) {
        float mv = vv[0]; int mi = ii[0]; int ms = 0;
#pragma unroll
        for (int k = 1; k < 6; ++k)
            if (vv[k] < mv || (vv[k] == mv && ii[k] < mi)) { mv = vv[k]; mi = ii[k]; ms = k; }
        float bv = mv; int bi = mi; int bl = lane;
#pragma unroll
        for (int off = 32; off; off >>= 1) {
            float ov = __shfl_xor(bv, off);
            int   oi = __shfl_xor(bi, off);
            int   ol = __shfl_xor(bl, off);
            if (ov < bv || (ov == bv && oi < bi)) { bv = ov; bi = oi; bl = ol; }
        }
        if (it > 0 && lane == 0) knn[(size_t)row * KNN + it - 1] = bi;
        if (lane == bl) {
#pragma unroll
            for (int k = 0; k < 6; ++k)
                if (k == ms) vv[k] = INF_F;
        }
    }
}

// ---------------- overlap + rank + per-pair partial loss ----------------
__global__ __launch_bounds__(64) void overlap_k(const int* __restrict__ knn,
                                                const int* __restrict__ pairs,
                                                const float* __restrict__ refso,
                                                float* __restrict__ partial) {
    const int p    = blockIdx.x;
    const int lane = threadIdx.x;
    __shared__ int si[KNN];
    const int i = pairs[p];
    if (lane < KNN) si[lane] = knn[(size_t)i * KNN + lane];
    __syncthreads();

    float v = 0.f;
    if (lane < KNN) {
        const int j = si[lane];
        int t[KNN];
        const int4* kj = reinterpret_cast<const int4*>(knn + (size_t)j * KNN);
#pragma unroll
        for (int b = 0; b < KNN / 4; ++b) {
            int4 q = kj[b];
            t[4 * b + 0] = q.x; t[4 * b + 1] = q.y;
            t[4 * b + 2] = q.z; t[4 * b + 3] = q.w;
        }
        int cnt = 0;
        for (int a = 0; a < KNN; ++a) {
            int sa = si[a];
#pragma unroll
            for (int b = 0; b < KNN; ++b) cnt += (t[b] == sa);
        }
        v = (float)cnt * (1.0f / KNN);
    }
    int rank = 0;
    for (int q = 0; q < KNN; ++q) {
        float ov = __shfl(v, q);
        rank += (lane < KNN) && ((ov < v) || (ov == v && q < lane));
    }
    float err = 0.f;
    if (lane < KNN) {
        float r = refso[(size_t)p * KNN + rank];
        float d = v - r;
        err = d * d;
    }
#pragma unroll
    for (int off = 32; off; off >>= 1) err += __shfl_xor(err, off);
    if (lane == 0) partial[p] = err;
}

// ---------------- deterministic final reduce ----------------
__global__ __launch_bounds__(256) void final_k(const float* __restrict__ partial,
                                               float* __restrict__ out) {
    const int tid = threadIdx.x;
    float a = 0.f;
    for (int q = tid; q < NPAIR; q += 256) a += partial[q];
#pragma unroll
    for (int off = 32; off; off >>= 1) a += __shfl_xor(a, off);
    __shared__ float red[4];
    if ((tid & 63) == 0) red[tid >> 6] = a;
    __syncthreads();
    if (tid == 0)
        out[0] = (red[0] + red[1] + red[2] + red[3]) * (1.0f / (NPAIR * KNN));
}

// ================= round-1 fallback (used only if ws too small) =================
__global__ __launch_bounds__(256) void dist_topk_k(const float* __restrict__ E,
                                                   const float* __restrict__ sq,
                                                   int* __restrict__ knn) {
    extern __shared__ float sc[];
    const int tid = threadIdx.x;
    const int r0  = blockIdx.x * 4;
    const float4* a0 = reinterpret_cast<const float4*>(E + (size_t)(r0 + 0) * DIM);
    const float4* a1 = reinterpret_cast<const float4*>(E + (size_t)(r0 + 1) * DIM);
    const float4* a2 = reinterpret_cast<const float4*>(E + (size_t)(r0 + 2) * DIM);
    const float4* a3 = reinterpret_cast<const float4*>(E + (size_t)(r0 + 3) * DIM);
    for (int tile = 0; tile < NROWS / 256; ++tile) {
        int j = tile * 256 + tid;
        const float4* bj = reinterpret_cast<const float4*>(E + (size_t)j * DIM);
        float acc0 = 0.f, acc1 = 0.f, acc2 = 0.f, acc3 = 0.f;
#pragma unroll 4
        for (int dd = 0; dd < DIM / 4; ++dd) {
            float4 b  = bj[dd];
            float4 x0 = a0[dd], x1 = a1[dd], x2 = a2[dd], x3 = a3[dd];
            acc0 += x0.x * b.x + x0.y * b.y + x0.z * b.z + x0.w * b.w;
            acc1 += x1.x * b.x + x1.y * b.y + x1.z * b.z + x1.w * b.w;
            acc2 += x2.x * b.x + x2.y * b.y + x2.z * b.z + x2.w * b.w;
            acc3 += x3.x * b.x + x3.y * b.y + x3.z * b.z + x3.w * b.w;
        }
        float sj = sq[j];
        sc[0 * NROWS + j] = sj - 2.f * acc0;
        sc[1 * NROWS + j] = sj - 2.f * acc1;
        sc[2 * NROWS + j] = sj - 2.f * acc2;
        sc[3 * NROWS + j] = sj - 2.f * acc3;
    }
    __syncthreads();
    const int w    = tid >> 6;
    const int lane = tid & 63;
    float* s = sc + w * NROWS;
    const float INF = __builtin_inff();
    float m[4]; int mi[4];
#pragma unroll
    for (int b = 0; b < 4; ++b) {
        float bm = INF; int bmi = NROWS;
        for (int t = 0; t < 32; ++t) {
            int j = lane + 64 * (b * 32 + t);
            float v = s[j];
            if (v < bm || (v == bm && j < bmi)) { bm = v; bmi = j; }
        }
        m[b] = bm; mi[b] = bmi;
    }
    const int row = r0 + w;
    for (int it = 0; it < KNN + 1; ++it) {
        float cvv = m[0]; int cii = mi[0];
#pragma unroll
        for (int b = 1; b < 4; ++b)
            if (m[b] < cvv || (m[b] == cvv && mi[b] < cii)) { cvv = m[b]; cii = mi[b]; }
        float bv = cvv; int bi = cii;
#pragma unroll
        for (int off = 32; off; off >>= 1) {
            float ov = __shfl_xor(bv, off);
            int   oi = __shfl_xor(bi, off);
            if (ov < bv || (ov == bv && oi < bi)) { bv = ov; bi = oi; }
        }
        if (it > 0 && lane == 0) knn[(size_t)row * KNN + (it - 1)] = bi;
        int ol = bi & 63;
        if (lane == ol) {
            s[bi] = INF;
            int b = (bi >> 6) >> 5;
            float bm = INF; int bmi = NROWS;
            for (int t = 0; t < 32; ++t) {
                int j = lane + 64 * (b * 32 + t);
                float v = s[j];
                if (v < bm || (v == bm && j < bmi)) { bm = v; bmi = j; }
            }
            m[b] = bm; mi[b] = bmi;
        }
    }
}

extern "C" void kernel_launch(void* const* d_in, const int* in_sizes, int n_in,
                              void* d_out, int out_size, void* d_ws, size_t ws_size,
                              hipStream_t stream) {
    const float* E     = (const float*)d_in[0];
    const float* refso = (const float*)d_in[1];
    const int*   pairs = (const int*)d_in[2];
    float* out = (float*)d_out;

    char* ws = (char*)d_ws;
    float* sq      = (float*)ws;                         // 32 KB
    float* partial = (float*)(ws + 32768);               // 8 KB
    int*   knn     = (int*)(ws + 40960);                 // 1 MB
    short* Phi     = (short*)(ws + 1089536);             // 8 MB packed hi
    short* Plo     = (short*)(ws + 9478144);             // 8 MB packed lo
    float* cval    = (float*)(ws + 17866752);            // 8192*384*4 = 12.58 MB
    int*   cidx    = (int*)(ws + 30449664);              // 12.58 MB
    const size_t NEED = 43032576;

    if (ws_size >= NEED) {
        hipFuncSetAttribute((const void*)distsel_k,
                            hipFuncAttributeMaxDynamicSharedMemorySize, 65536);
        sqnorm_k<<<NROWS / 4, 256, 0, stream>>>(E, sq);
        prep_k<<<NROWS * DIM / 8 / 256, 256, 0, stream>>>(E, Phi, Plo);
        distsel_k<<<(NROWS / MROWS) * STRIPS, 512, 65536, stream>>>(Phi, Plo, sq, cval, cidx);
        merge_k<<<NROWS / 4, 256, 0, stream>>>(cval, cidx, knn);
    } else {
        hipFuncSetAttribute((const void*)dist_topk_k,
                            hipFuncAttributeMaxDynamicSharedMemorySize, 131072);
        sqnorm_k<<<NROWS / 4, 256, 0, stream>>>(E, sq);
        dist_topk_k<<<NROWS / 4, 256, 131072, stream>>>(E, sq, knn);
    }
    overlap_k<<<NPAIR, 64, 0, stream>>>(knn, pairs, refso, partial);
    final_k<<<1, 256, 0, stream>>>(partial, out);
}